// Round 8
// baseline (189.786 us; speedup 1.0000x reference)
//
#include <hip/hip_runtime.h>
#include <hip/hip_bf16.h>

#define SEQ   101
#define BATCH 16384
#define INP   9
#define HID   32
#define NOUT  3
#define HSlin 3232          // HID*SEQ
#define SB    (SEQ * BATCH) // flattened (s,b) cols

typedef __attribute__((ext_vector_type(8))) short short8;     // 8 bf16 (4 VGPRs)
typedef __attribute__((ext_vector_type(4))) float f32x4;      // MFMA C/D
typedef __attribute__((ext_vector_type(4))) unsigned u32x4;

#define LOG2E   1.4426950408889634f
#define N2LOG2E (-2.8853900817779268f)

__device__ __forceinline__ unsigned hi16_of(float f) {        // truncate to bf16
    return __float_as_uint(f) >> 16;
}
__device__ __forceinline__ unsigned lo16_of(float f) {        // residual as bf16
    unsigned u = __float_as_uint(f);
    float lo = f - __uint_as_float(u & 0xffff0000u);
    return __float_as_uint(lo) >> 16;
}
// one v_perm_b32: bf16-trunc of a -> bits[15:0], b -> bits[31:16]
__device__ __forceinline__ unsigned pack2(float a, float b) {
    return __builtin_amdgcn_perm(__float_as_uint(b), __float_as_uint(a), 0x07060302u);
}
__device__ __forceinline__ float losub(float f) {             // bf16 residual as float
    return f - __uint_as_float(__float_as_uint(f) & 0xffff0000u);
}

// Swapped-operand scheme: gates^T = W * [x|h]^T  (verified R4-R7).
// Weights pre-scaled by log2e (i,f,o) / 2*log2e (g) so activations use raw exp2.
__global__ void prep_kernel(const float* __restrict__ W_ih, const float* __restrict__ W_hh,
                            const float* __restrict__ b_ih, const float* __restrict__ b_hh,
                            unsigned short* __restrict__ whh_hi, unsigned short* __restrict__ whh_lo,
                            unsigned short* __restrict__ wih, float* __restrict__ biasc) {
    int tid = threadIdx.x;            // 0..511 : t = tid>>6, l = tid&63
    int l   = tid & 63;
    int t   = tid >> 6;
    int row = l & 15;                 // gate-in-tile
    int g   = l >> 4;
    int gate = 16 * t + row;
    float sc = ((gate >> 5) == 2) ? (2.f * LOG2E) : LOG2E;    // g-gate: tanh needs e^{-2g}
    for (int j = 0; j < 8; ++j) {
        int u = 4 * g + (j & 3) + 16 * (j >> 2);     // pi(8g+j)
        float whh = W_hh[gate * HID + u] * sc;
        whh_hi[tid * 8 + j] = (unsigned short)hi16_of(whh);
        whh_lo[tid * 8 + j] = (unsigned short)lo16_of(whh);
        int k = 8 * g + j;
        const float* Wr = W_ih + gate * INP;
        unsigned v;
        if      (k < 8)   v = hi16_of(Wr[k] * sc);
        else if (k < 16)  v = lo16_of(Wr[k - 8] * sc);
        else if (k < 24)  v = hi16_of(Wr[k - 16] * sc);
        else if (k == 24) v = hi16_of(Wr[8] * sc);
        else if (k == 25) v = lo16_of(Wr[8] * sc);
        else if (k == 26) v = hi16_of(Wr[8] * sc);
        else              v = 0u;
        wih[tid * 8 + j] = (unsigned short)v;
    }
    if (tid < 4 * HID) {
        float bs = ((tid >> 5) == 2) ? (2.f * LOG2E) : LOG2E;
        biasc[tid] = (b_ih[tid] + b_hh[tid]) * bs;
    }
}

// Emit the staged W_lin partials for one step (base psb = s*BATCH + b0).
// Lanes 0..15 hold duplicated col sums after xor16/xor32 (cols 8-15 = 0-7).
template<bool PLANES>
__device__ __forceinline__ void emit_prev(float p0, float p1, float p2,
                                          unsigned psb, float* __restrict__ dataout,
                                          int lane, int cr) {
    p0 += __shfl_xor(p0, 16); p1 += __shfl_xor(p1, 16); p2 += __shfl_xor(p2, 16);
    p0 += __shfl_xor(p0, 32); p1 += __shfl_xor(p1, 32); p2 += __shfl_xor(p2, 32);
    if (PLANES) {
        if (lane < 8) {
            unsigned blk = psb + (unsigned)lane;
            dataout[0 * SB + blk] = p0;
            dataout[1 * SB + blk] = p1;
            dataout[2 * SB + blk] = p2;
        }
    } else {
        // fallback: <=2 output rows across the 8 cols; butterfly over 8 cols
        unsigned blk  = psb + (unsigned)cr;
        unsigned r    = blk / 101u;
        unsigned rmin = psb / 101u;
        bool low = (r == rmin);
        float a0 = low ? p0 : 0.f, a1 = low ? p1 : 0.f, a2 = low ? p2 : 0.f;
        float d0 = low ? 0.f : p0, d1 = low ? 0.f : p1, d2 = low ? 0.f : p2;
#pragma unroll
        for (int m = 1; m < 8; m <<= 1) {
            a0 += __shfl_xor(a0, m); a1 += __shfl_xor(a1, m); a2 += __shfl_xor(a2, m);
            d0 += __shfl_xor(d0, m); d1 += __shfl_xor(d1, m); d2 += __shfl_xor(d2, m);
        }
        int anyhi = __any(!low && lane < 8);
        if (lane == 0) {
            atomicAdd(&dataout[rmin * 3 + 0], a0);
            atomicAdd(&dataout[rmin * 3 + 1], a1);
            atomicAdd(&dataout[rmin * 3 + 2], a2);
            if (anyhi) {   // rmin+1 may be BATCH only when d==0; accp has pad slots
                atomicAdd(&dataout[(rmin + 1u) * 3 + 0], d0);
                atomicAdd(&dataout[(rmin + 1u) * 3 + 1], d1);
                atomicAdd(&dataout[(rmin + 1u) * 3 + 2], d2);
            }
        }
    }
}

// One INDEPENDENT wave per 8 batch rows — no barriers, no cross-wave traffic.
// 2048 waves = 2 waves/SIMD; each wave's stalls hide under the other's issue.
// Lanes with c>=8 duplicate cols 0-7 (same addresses, no extra HBM traffic).
template<bool PLANES>
__global__ __launch_bounds__(64, 2) void lstm_kernel(
    const float* __restrict__ x,                 // [SEQ][BATCH][INP]
    const unsigned short* __restrict__ whh_hi_g, // [8][64][8] A-frags
    const unsigned short* __restrict__ whh_lo_g,
    const unsigned short* __restrict__ wih_g,
    const float* __restrict__ biasc,             // [4H] (pre-scaled)
    const float* __restrict__ W_lin,             // [NOUT][HSlin]
    float* __restrict__ dataout)                 // planes [3][SB]  (or accp fallback)
{
    const int lane = threadIdx.x;
    const int c    = lane & 15;        // MFMA batch col
    const int cr   = c & 7;            // real batch col (8-15 duplicate 0-7)
    const int g    = lane >> 4;
    const int b0   = blockIdx.x * 8;
    const int b    = b0 + cr;

    // Static A-fragments + per-lane bias quads (live across all steps)
    short8 whi[8], wlo[8], xw[8];
    f32x4 biasv[8];
#pragma unroll
    for (int t = 0; t < 8; ++t) {
        whi[t] = *reinterpret_cast<const short8*>(whh_hi_g + (t * 64 + lane) * 8);
        wlo[t] = *reinterpret_cast<const short8*>(whh_lo_g + (t * 64 + lane) * 8);
        xw[t]  = *reinterpret_cast<const short8*>(wih_g    + (t * 64 + lane) * 8);
        biasv[t] = *reinterpret_cast<const f32x4*>(biasc + 16 * t + 4 * g);
    }

    const bool g01 = (g < 2), g2 = (g == 2);

    float cst[2][4] = {{0.f,0.f,0.f,0.f},{0.f,0.f,0.f,0.f}};
    float hlc[2][4] = {{0.f,0.f,0.f,0.f},{0.f,0.f,0.f,0.f}};  // h[half][q]: unit 16*half+4g+q
    float xv[9];
    {
        const float* xp = x + (size_t)b * INP;           // s = 0
#pragma unroll
        for (int i = 0; i < 9; ++i) xv[i] = xp[i];
    }

    float pp0 = 0.f, pp1 = 0.f, pp2 = 0.f;               // staged W_lin partials
    unsigned psb = 0;

#pragma unroll 1
    for (int s = 0; s < SEQ; ++s) {
        // (0) this step's W_lin weights (issued early, consumed after activations)
        unsigned blk  = (unsigned)s * BATCH + (unsigned)b;
        unsigned r    = blk / 101u;
        unsigned slot = blk - r * 101u;
        const float* wl = W_lin + slot * HID + 4 * g;
        float4 w0a = *(const float4*)(wl);
        float4 w0b = *(const float4*)(wl + 16);
        float4 w1a = *(const float4*)(wl + HSlin);
        float4 w1b = *(const float4*)(wl + HSlin + 16);
        float4 w2a = *(const float4*)(wl + 2 * HSlin);
        float4 w2b = *(const float4*)(wl + 2 * HSlin + 16);

        // (1) packed-x B fragment (v_perm packing, per-g select)
        short8 xa;
        {
            unsigned hp0 = pack2(xv[0], xv[1]), hp1 = pack2(xv[2], xv[3]);
            unsigned hp2 = pack2(xv[4], xv[5]), hp3 = pack2(xv[6], xv[7]);
            unsigned lp0 = pack2(losub(xv[0]), losub(xv[1])), lp1 = pack2(losub(xv[2]), losub(xv[3]));
            unsigned lp2 = pack2(losub(xv[4]), losub(xv[5])), lp3 = pack2(losub(xv[6]), losub(xv[7]));
            unsigned h8h8 = pack2(xv[8], xv[8]);
            unsigned l8w  = __float_as_uint(losub(xv[8])) >> 16;
            u32x4 xt;
            xt[0] = g01 ? hp0 : (g2 ? lp0 : h8h8);
            xt[1] = g01 ? hp1 : (g2 ? lp1 : l8w);
            xt[2] = g01 ? hp2 : (g2 ? lp2 : 0u);
            xt[3] = g01 ? hp3 : (g2 ? lp3 : 0u);
            xa = __builtin_bit_cast(short8, xt);
        }
        // (2) h B-fragment = own h, hi/lo via v_perm (zero cross-lane movement)
        short8 bh, bl;
        {
            u32x4 ph, pl;
            ph[0] = pack2(hlc[0][0], hlc[0][1]); ph[1] = pack2(hlc[0][2], hlc[0][3]);
            ph[2] = pack2(hlc[1][0], hlc[1][1]); ph[3] = pack2(hlc[1][2], hlc[1][3]);
            pl[0] = pack2(losub(hlc[0][0]), losub(hlc[0][1]));
            pl[1] = pack2(losub(hlc[0][2]), losub(hlc[0][3]));
            pl[2] = pack2(losub(hlc[1][0]), losub(hlc[1][1]));
            pl[3] = pack2(losub(hlc[1][2]), losub(hlc[1][3]));
            bh = __builtin_bit_cast(short8, ph);
            bl = __builtin_bit_cast(short8, pl);
        }
        // (3) gates^T: 8 tiles x 4 MFMA
        f32x4 acc[8];
#pragma unroll
        for (int t = 0; t < 8; ++t) {
            acc[t] = __builtin_amdgcn_mfma_f32_16x16x32_bf16(whi[t], bh, biasv[t], 0, 0, 0);
            acc[t] = __builtin_amdgcn_mfma_f32_16x16x32_bf16(wlo[t], bh, acc[t],   0, 0, 0);
            acc[t] = __builtin_amdgcn_mfma_f32_16x16x32_bf16(whi[t], bl, acc[t],   0, 0, 0);
            acc[t] = __builtin_amdgcn_mfma_f32_16x16x32_bf16(xw[t],  xa, acc[t],   0, 0, 0);
        }
        // (4) previous step's reduce + stores — hides under MFMA latency
        if (s > 0) emit_prev<PLANES>(pp0, pp1, pp2, psb, dataout, lane, cr);

        // (5) prefetch next step's x
        float xn[9];
        if (s < SEQ - 1) {
            const float* xpn = x + ((size_t)(s + 1) * BATCH + b) * INP;
#pragma unroll
            for (int i = 0; i < 9; ++i) xn[i] = xpn[i];
        }

        // (6) activations (pre-scaled gates: raw exp2)
#pragma unroll
        for (int half = 0; half < 2; ++half) {
#pragma unroll
            for (int q = 0; q < 4; ++q) {
                float iv = acc[0 + half][q], fv = acc[2 + half][q];
                float gv = acc[4 + half][q], ov = acc[6 + half][q];
                float ef = __builtin_amdgcn_exp2f(-fv);
                float sf = __builtin_amdgcn_rcpf(1.f + ef);
                float ei = __builtin_amdgcn_exp2f(-iv);
                float eg = __builtin_amdgcn_exp2f(-gv);              // e^{-2g}
                float st = (1.f - eg) * __builtin_amdgcn_rcpf((1.f + ei) * (1.f + eg));
                float cn = fmaf(sf, cst[half][q], st);
                cst[half][q] = cn;
                float eo = __builtin_amdgcn_exp2f(-ov);
                float ec = __builtin_amdgcn_exp2f(cn * N2LOG2E);     // e^{-2c}
                hlc[half][q] = (1.f - ec) * __builtin_amdgcn_rcpf((1.f + eo) * (1.f + ec));
            }
        }
        if (s < SEQ - 1) {
#pragma unroll
            for (int i = 0; i < 9; ++i) xv[i] = xn[i];
        }

        // (7) this step's W_lin partials (units 4g+q <- half0, 16+4g+q <- half1)
        pp0 = w0a.x*hlc[0][0] + w0a.y*hlc[0][1] + w0a.z*hlc[0][2] + w0a.w*hlc[0][3]
            + w0b.x*hlc[1][0] + w0b.y*hlc[1][1] + w0b.z*hlc[1][2] + w0b.w*hlc[1][3];
        pp1 = w1a.x*hlc[0][0] + w1a.y*hlc[0][1] + w1a.z*hlc[0][2] + w1a.w*hlc[0][3]
            + w1b.x*hlc[1][0] + w1b.y*hlc[1][1] + w1b.z*hlc[1][2] + w1b.w*hlc[1][3];
        pp2 = w2a.x*hlc[0][0] + w2a.y*hlc[0][1] + w2a.z*hlc[0][2] + w2a.w*hlc[0][3]
            + w2b.x*hlc[1][0] + w2b.y*hlc[1][1] + w2b.z*hlc[1][2] + w2b.w*hlc[1][3];
        psb = (unsigned)s * BATCH + (unsigned)b0;
    }
    // epilogue: emit for s = SEQ-1
    emit_prev<PLANES>(pp0, pp1, pp2, psb, dataout, lane, cr);
}

// Plane path: one wave per output row sums its 101 contiguous cols.
__global__ void finalize_planes(const float* __restrict__ planes, const float* __restrict__ b_lin,
                                float* __restrict__ out) {
    int wid = (blockIdx.x * blockDim.x + threadIdx.x) >> 6;   // row 0..16383
    int l   = threadIdx.x & 63;
    float v[3];
#pragma unroll
    for (int o = 0; o < 3; ++o) {
        const float* p = planes + (size_t)o * SB + (size_t)wid * 101;
        float t = p[l] + ((l < 37) ? p[l + 64] : 0.f);
#pragma unroll
        for (int m = 1; m < 64; m <<= 1) t += __shfl_xor(t, m);
        v[o] = t;
    }
    if (l == 0) {
        out[wid * 3 + 0] = v[0] + b_lin[0];
        out[wid * 3 + 1] = v[1] + b_lin[1];
        out[wid * 3 + 2] = v[2] + b_lin[2];
    }
}

__global__ void finalize_acc(const float* __restrict__ acc, const float* __restrict__ b_lin,
                             float* __restrict__ out) {
    int i = blockIdx.x * blockDim.x + threadIdx.x;
    if (i < BATCH * NOUT) {
        int r = i / 3;
        int o = i - r * 3;
        out[i] = acc[i] + b_lin[o];
    }
}

extern "C" void kernel_launch(void* const* d_in, const int* in_sizes, int n_in,
                              void* d_out, int out_size, void* d_ws, size_t ws_size,
                              hipStream_t stream) {
    const float* x     = (const float*)d_in[0];
    const float* W_ih  = (const float*)d_in[1];
    const float* W_hh  = (const float*)d_in[2];
    const float* b_ih  = (const float*)d_in[3];
    const float* b_hh  = (const float*)d_in[4];
    const float* W_lin = (const float*)d_in[5];
    const float* b_lin = (const float*)d_in[6];
    float* out = (float*)d_out;

    // ws: whh_hi[4096]u16 | whh_lo[4096]u16 | wih[4096]u16 | biasc[128]f32 | data...
    unsigned short* whh_hi = (unsigned short*)d_ws;
    unsigned short* whh_lo = whh_hi + 4096;
    unsigned short* wih    = whh_lo + 4096;
    float* biasc = (float*)(wih + 4096);
    float* data  = (float*)((char*)d_ws + 25600);

    size_t need_planes = 25600 + (size_t)3 * SB * sizeof(float);
    bool planes = ws_size >= need_planes;

    hipLaunchKernelGGL(prep_kernel, dim3(1), dim3(512), 0, stream,
                       W_ih, W_hh, b_ih, b_hh, whh_hi, whh_lo, wih, biasc);
    if (planes) {
        hipLaunchKernelGGL((lstm_kernel<true>), dim3(BATCH / 8), dim3(64), 0, stream,
                           x, whh_hi, whh_lo, wih, biasc, W_lin, data);
        hipLaunchKernelGGL(finalize_planes, dim3(BATCH / 4), dim3(256), 0, stream,
                           data, b_lin, out);
    } else {
        hipMemsetAsync(data, 0, 49160 * sizeof(float), stream);
        hipLaunchKernelGGL((lstm_kernel<false>), dim3(BATCH / 8), dim3(64), 0, stream,
                           x, whh_hi, whh_lo, wih, biasc, W_lin, data);
        hipLaunchKernelGGL(finalize_acc, dim3((BATCH * NOUT + 255) / 256), dim3(256), 0, stream,
                           data, b_lin, out);
    }
}

// Round 9
// 157.961 us; speedup vs baseline: 1.2015x; 1.2015x over previous
//
#include <hip/hip_runtime.h>
#include <hip/hip_bf16.h>

#define SEQ   101
#define BATCH 16384
#define INP   9
#define HID   32
#define NOUT  3
#define HSlin 3232          // HID*SEQ
#define SB    (SEQ * BATCH) // flattened (s,b) cols

typedef __attribute__((ext_vector_type(8))) short short8;     // 8 bf16 (4 VGPRs)
typedef __attribute__((ext_vector_type(4))) float f32x4;      // MFMA C/D
typedef __attribute__((ext_vector_type(4))) unsigned u32x4;

#define LOG2E   1.4426950408889634f
#define N2LOG2E (-2.8853900817779268f)

__device__ __forceinline__ unsigned hi16_of(float f) {        // truncate to bf16
    return __float_as_uint(f) >> 16;
}
__device__ __forceinline__ unsigned lo16_of(float f) {        // residual as bf16
    unsigned u = __float_as_uint(f);
    float lo = f - __uint_as_float(u & 0xffff0000u);
    return __float_as_uint(lo) >> 16;
}
// one v_perm_b32: bf16-trunc of a -> bits[15:0], b -> bits[31:16]
__device__ __forceinline__ unsigned pack2(float a, float b) {
    return __builtin_amdgcn_perm(__float_as_uint(b), __float_as_uint(a), 0x07060302u);
}
__device__ __forceinline__ float losub(float f) {             // bf16 residual as float
    return f - __uint_as_float(__float_as_uint(f) & 0xffff0000u);
}

// Swapped-operand scheme: gates^T = W * [x|h]^T  (verified R4-R8).
// Weights pre-scaled by log2e (i,f,o) / 2*log2e (g) so activations use raw exp2.
__global__ void prep_kernel(const float* __restrict__ W_ih, const float* __restrict__ W_hh,
                            const float* __restrict__ b_ih, const float* __restrict__ b_hh,
                            unsigned short* __restrict__ whh_hi, unsigned short* __restrict__ whh_lo,
                            unsigned short* __restrict__ wih, float* __restrict__ biasc) {
    int tid = threadIdx.x;            // 0..511 : t = tid>>6, l = tid&63
    int l   = tid & 63;
    int t   = tid >> 6;
    int row = l & 15;                 // gate-in-tile
    int g   = l >> 4;
    int gate = 16 * t + row;
    float sc = ((gate >> 5) == 2) ? (2.f * LOG2E) : LOG2E;    // g-gate: tanh needs e^{-2g}
    for (int j = 0; j < 8; ++j) {
        int u = 4 * g + (j & 3) + 16 * (j >> 2);     // pi(8g+j)
        float whh = W_hh[gate * HID + u] * sc;
        whh_hi[tid * 8 + j] = (unsigned short)hi16_of(whh);
        whh_lo[tid * 8 + j] = (unsigned short)lo16_of(whh);
        int k = 8 * g + j;
        const float* Wr = W_ih + gate * INP;
        unsigned v;
        if      (k < 8)   v = hi16_of(Wr[k] * sc);
        else if (k < 16)  v = lo16_of(Wr[k - 8] * sc);
        else if (k < 24)  v = hi16_of(Wr[k - 16] * sc);
        else if (k == 24) v = hi16_of(Wr[8] * sc);
        else if (k == 25) v = lo16_of(Wr[8] * sc);
        else if (k == 26) v = hi16_of(Wr[8] * sc);
        else              v = 0u;
        wih[tid * 8 + j] = (unsigned short)v;
    }
    if (tid < 4 * HID) {
        float bs = ((tid >> 5) == 2) ? (2.f * LOG2E) : LOG2E;
        biasc[tid] = (b_ih[tid] + b_hh[tid]) * bs;
    }
}

// Emit staged W_lin partials (base psb = s*BATCH + b0). Dots are split by
// lane-half (own 4 units each); xor8 merges halves, xor16/32 merge g-groups.
template<bool PLANES>
__device__ __forceinline__ void emit_prev(float p0, float p1, float p2,
                                          unsigned psb, float* __restrict__ dataout,
                                          int lane, int cr) {
    p0 += __shfl_xor(p0, 8);  p1 += __shfl_xor(p1, 8);  p2 += __shfl_xor(p2, 8);
    p0 += __shfl_xor(p0, 16); p1 += __shfl_xor(p1, 16); p2 += __shfl_xor(p2, 16);
    p0 += __shfl_xor(p0, 32); p1 += __shfl_xor(p1, 32); p2 += __shfl_xor(p2, 32);
    if (PLANES) {
        if (lane < 8) {
            unsigned blk = psb + (unsigned)lane;
            dataout[0 * SB + blk] = p0;
            dataout[1 * SB + blk] = p1;
            dataout[2 * SB + blk] = p2;
        }
    } else {
        // fallback: <=2 output rows across the 8 cols; butterfly over 8 cols
        unsigned blk  = psb + (unsigned)cr;
        unsigned r    = blk / 101u;
        unsigned rmin = psb / 101u;
        bool low = (r == rmin);
        float a0 = low ? p0 : 0.f, a1 = low ? p1 : 0.f, a2 = low ? p2 : 0.f;
        float d0 = low ? 0.f : p0, d1 = low ? 0.f : p1, d2 = low ? 0.f : p2;
#pragma unroll
        for (int m = 1; m < 8; m <<= 1) {
            a0 += __shfl_xor(a0, m); a1 += __shfl_xor(a1, m); a2 += __shfl_xor(a2, m);
            d0 += __shfl_xor(d0, m); d1 += __shfl_xor(d1, m); d2 += __shfl_xor(d2, m);
        }
        int anyhi = __any(!low && lane < 8);
        if (lane == 0) {
            atomicAdd(&dataout[rmin * 3 + 0], a0);
            atomicAdd(&dataout[rmin * 3 + 1], a1);
            atomicAdd(&dataout[rmin * 3 + 2], a2);
            if (anyhi) {
                atomicAdd(&dataout[(rmin + 1u) * 3 + 0], d0);
                atomicAdd(&dataout[(rmin + 1u) * 3 + 1], d1);
                atomicAdd(&dataout[(rmin + 1u) * 3 + 2], d2);
            }
        }
    }
}

// One INDEPENDENT wave per 8 batch rows (cols 8-15 duplicate 0-7), no barriers.
// NEW vs R8: activations split by lane-half — lanes c<8 process half0 units
// (even tiles), c>=8 half1 (odd tiles); 4x shfl_xor(8) exchanges h so every
// lane can build its full B-fragment. W_lin loads/dots also halved per lane.
template<bool PLANES>
__global__ __launch_bounds__(64, 2) void lstm_kernel(
    const float* __restrict__ x,                 // [SEQ][BATCH][INP]
    const unsigned short* __restrict__ whh_hi_g, // [8][64][8] A-frags
    const unsigned short* __restrict__ whh_lo_g,
    const unsigned short* __restrict__ wih_g,
    const float* __restrict__ biasc,             // [4H] (pre-scaled)
    const float* __restrict__ W_lin,             // [NOUT][HSlin]
    float* __restrict__ dataout)                 // planes [3][SB] (or accp fallback)
{
    const int lane = threadIdx.x;
    const int c    = lane & 15;        // MFMA batch col
    const int cr   = c & 7;            // real batch col (8-15 duplicate 0-7)
    const bool hi8 = (lane & 8) != 0;  // this lane owns half1 (units 16+4g+q)
    const int g    = lane >> 4;
    const int b0   = blockIdx.x * 8;
    const int b    = b0 + cr;

    // Static A-fragments + per-lane bias quads (live across all steps)
    short8 whi[8], wlo[8], xw[8];
    f32x4 biasv[8];
#pragma unroll
    for (int t = 0; t < 8; ++t) {
        whi[t] = *reinterpret_cast<const short8*>(whh_hi_g + (t * 64 + lane) * 8);
        wlo[t] = *reinterpret_cast<const short8*>(whh_lo_g + (t * 64 + lane) * 8);
        xw[t]  = *reinterpret_cast<const short8*>(wih_g    + (t * 64 + lane) * 8);
        biasv[t] = *reinterpret_cast<const f32x4*>(biasc + 16 * t + 4 * g);
    }

    const bool g01 = (g < 2), g2 = (g == 2);

    float cst[4]  = {0.f, 0.f, 0.f, 0.f};        // c-state: my half's 4 units
    float hown[4] = {0.f, 0.f, 0.f, 0.f};        // my half's h (for W_lin dot)
    float h0q[4]  = {0.f, 0.f, 0.f, 0.f};        // full h after exchange
    float h1q[4]  = {0.f, 0.f, 0.f, 0.f};
    float xv[9];
    {
        const float* xp = x + (size_t)b * INP;           // s = 0
#pragma unroll
        for (int i = 0; i < 9; ++i) xv[i] = xp[i];
    }

    float pp0 = 0.f, pp1 = 0.f, pp2 = 0.f;               // staged W_lin partials
    unsigned psb = 0;

#pragma unroll 1
    for (int s = 0; s < SEQ; ++s) {
        // (0) this step's W_lin weights — only my half's 4 columns per plane
        unsigned blk  = (unsigned)s * BATCH + (unsigned)b;
        unsigned r    = blk / 101u;
        unsigned slot = blk - r * 101u;
        const float* wl = W_lin + slot * HID + 4 * g + (hi8 ? 16 : 0);
        float4 w0 = *(const float4*)(wl);
        float4 w1 = *(const float4*)(wl + HSlin);
        float4 w2 = *(const float4*)(wl + 2 * HSlin);

        // (1) packed-x B fragment (v_perm packing, per-g select)
        short8 xa;
        {
            unsigned hp0 = pack2(xv[0], xv[1]), hp1 = pack2(xv[2], xv[3]);
            unsigned hp2 = pack2(xv[4], xv[5]), hp3 = pack2(xv[6], xv[7]);
            unsigned lp0 = pack2(losub(xv[0]), losub(xv[1])), lp1 = pack2(losub(xv[2]), losub(xv[3]));
            unsigned lp2 = pack2(losub(xv[4]), losub(xv[5])), lp3 = pack2(losub(xv[6]), losub(xv[7]));
            unsigned h8h8 = pack2(xv[8], xv[8]);
            unsigned l8w  = __float_as_uint(losub(xv[8])) >> 16;
            u32x4 xt;
            xt[0] = g01 ? hp0 : (g2 ? lp0 : h8h8);
            xt[1] = g01 ? hp1 : (g2 ? lp1 : l8w);
            xt[2] = g01 ? hp2 : (g2 ? lp2 : 0u);
            xt[3] = g01 ? hp3 : (g2 ? lp3 : 0u);
            xa = __builtin_bit_cast(short8, xt);
        }
        // (2) h B-fragment from exchanged full h (zero extra cross-lane beyond xor8)
        short8 bh, bl;
        {
            u32x4 ph, pl;
            ph[0] = pack2(h0q[0], h0q[1]); ph[1] = pack2(h0q[2], h0q[3]);
            ph[2] = pack2(h1q[0], h1q[1]); ph[3] = pack2(h1q[2], h1q[3]);
            pl[0] = pack2(losub(h0q[0]), losub(h0q[1]));
            pl[1] = pack2(losub(h0q[2]), losub(h0q[3]));
            pl[2] = pack2(losub(h1q[0]), losub(h1q[1]));
            pl[3] = pack2(losub(h1q[2]), losub(h1q[3]));
            bh = __builtin_bit_cast(short8, ph);
            bl = __builtin_bit_cast(short8, pl);
        }
        // (3) gates^T: 8 tiles x 4 MFMA
        f32x4 acc[8];
#pragma unroll
        for (int t = 0; t < 8; ++t) {
            acc[t] = __builtin_amdgcn_mfma_f32_16x16x32_bf16(whi[t], bh, biasv[t], 0, 0, 0);
            acc[t] = __builtin_amdgcn_mfma_f32_16x16x32_bf16(wlo[t], bh, acc[t],   0, 0, 0);
            acc[t] = __builtin_amdgcn_mfma_f32_16x16x32_bf16(whi[t], bl, acc[t],   0, 0, 0);
            acc[t] = __builtin_amdgcn_mfma_f32_16x16x32_bf16(xw[t],  xa, acc[t],   0, 0, 0);
        }
        // (4) previous step's reduce + stores — hides under MFMA latency
        if (s > 0) emit_prev<PLANES>(pp0, pp1, pp2, psb, dataout, lane, cr);

        // (5) prefetch next step's x
        float xn[9];
        if (s < SEQ - 1) {
            const float* xpn = x + ((size_t)(s + 1) * BATCH + b) * INP;
#pragma unroll
            for (int i = 0; i < 9; ++i) xn[i] = xpn[i];
        }

        // (6) activations for MY half only: select even/odd tiles (static idx +
        //     vector cndmask — no scratch), 4 units, 20 trans instead of 40.
        f32x4 aI = hi8 ? acc[1] : acc[0];
        f32x4 aF = hi8 ? acc[3] : acc[2];
        f32x4 aG = hi8 ? acc[5] : acc[4];
        f32x4 aO = hi8 ? acc[7] : acc[6];
#pragma unroll
        for (int q = 0; q < 4; ++q) {
            float ef = __builtin_amdgcn_exp2f(-aF[q]);
            float sf = __builtin_amdgcn_rcpf(1.f + ef);
            float ei = __builtin_amdgcn_exp2f(-aI[q]);
            float eg = __builtin_amdgcn_exp2f(-aG[q]);               // e^{-2g}
            float st = (1.f - eg) * __builtin_amdgcn_rcpf((1.f + ei) * (1.f + eg));
            float cn = fmaf(sf, cst[q], st);
            cst[q] = cn;
            float eo = __builtin_amdgcn_exp2f(-aO[q]);
            float ec = __builtin_amdgcn_exp2f(cn * N2LOG2E);         // e^{-2c}
            hown[q] = (1.f - ec) * __builtin_amdgcn_rcpf((1.f + eo) * (1.f + ec));
        }
        // (6b) exchange halves with the twin lane (c ^ 8) and order them
#pragma unroll
        for (int q = 0; q < 4; ++q) {
            float oth = __shfl_xor(hown[q], 8);
            h0q[q] = hi8 ? oth     : hown[q];
            h1q[q] = hi8 ? hown[q] : oth;
        }
        if (s < SEQ - 1) {
#pragma unroll
            for (int i = 0; i < 9; ++i) xv[i] = xn[i];
        }

        // (7) this step's W_lin partial — my half's 4 units only
        pp0 = w0.x * hown[0] + w0.y * hown[1] + w0.z * hown[2] + w0.w * hown[3];
        pp1 = w1.x * hown[0] + w1.y * hown[1] + w1.z * hown[2] + w1.w * hown[3];
        pp2 = w2.x * hown[0] + w2.y * hown[1] + w2.z * hown[2] + w2.w * hown[3];
        psb = (unsigned)s * BATCH + (unsigned)b0;
    }
    // epilogue: emit for s = SEQ-1
    emit_prev<PLANES>(pp0, pp1, pp2, psb, dataout, lane, cr);
}

// Plane path: one wave per output row sums its 101 contiguous cols.
__global__ void finalize_planes(const float* __restrict__ planes, const float* __restrict__ b_lin,
                                float* __restrict__ out) {
    int wid = (blockIdx.x * blockDim.x + threadIdx.x) >> 6;   // row 0..16383
    int l   = threadIdx.x & 63;
    float v[3];
#pragma unroll
    for (int o = 0; o < 3; ++o) {
        const float* p = planes + (size_t)o * SB + (size_t)wid * 101;
        float t = p[l] + ((l < 37) ? p[l + 64] : 0.f);
#pragma unroll
        for (int m = 1; m < 64; m <<= 1) t += __shfl_xor(t, m);
        v[o] = t;
    }
    if (l == 0) {
        out[wid * 3 + 0] = v[0] + b_lin[0];
        out[wid * 3 + 1] = v[1] + b_lin[1];
        out[wid * 3 + 2] = v[2] + b_lin[2];
    }
}

__global__ void finalize_acc(const float* __restrict__ acc, const float* __restrict__ b_lin,
                             float* __restrict__ out) {
    int i = blockIdx.x * blockDim.x + threadIdx.x;
    if (i < BATCH * NOUT) {
        int r = i / 3;
        int o = i - r * 3;
        out[i] = acc[i] + b_lin[o];
    }
}

extern "C" void kernel_launch(void* const* d_in, const int* in_sizes, int n_in,
                              void* d_out, int out_size, void* d_ws, size_t ws_size,
                              hipStream_t stream) {
    const float* x     = (const float*)d_in[0];
    const float* W_ih  = (const float*)d_in[1];
    const float* W_hh  = (const float*)d_in[2];
    const float* b_ih  = (const float*)d_in[3];
    const float* b_hh  = (const float*)d_in[4];
    const float* W_lin = (const float*)d_in[5];
    const float* b_lin = (const float*)d_in[6];
    float* out = (float*)d_out;

    // ws: whh_hi[4096]u16 | whh_lo[4096]u16 | wih[4096]u16 | biasc[128]f32 | data...
    unsigned short* whh_hi = (unsigned short*)d_ws;
    unsigned short* whh_lo = whh_hi + 4096;
    unsigned short* wih    = whh_lo + 4096;
    float* biasc = (float*)(wih + 4096);
    float* data  = (float*)((char*)d_ws + 25600);

    size_t need_planes = 25600 + (size_t)3 * SB * sizeof(float);
    bool planes = ws_size >= need_planes;

    hipLaunchKernelGGL(prep_kernel, dim3(1), dim3(512), 0, stream,
                       W_ih, W_hh, b_ih, b_hh, whh_hi, whh_lo, wih, biasc);
    if (planes) {
        hipLaunchKernelGGL((lstm_kernel<true>), dim3(BATCH / 8), dim3(64), 0, stream,
                           x, whh_hi, whh_lo, wih, biasc, W_lin, data);
        hipLaunchKernelGGL(finalize_planes, dim3(BATCH / 4), dim3(256), 0, stream,
                           data, b_lin, out);
    } else {
        hipMemsetAsync(data, 0, 49160 * sizeof(float), stream);
        hipLaunchKernelGGL((lstm_kernel<false>), dim3(BATCH / 8), dim3(64), 0, stream,
                           x, whh_hi, whh_lo, wih, biasc, W_lin, data);
        hipLaunchKernelGGL(finalize_acc, dim3((BATCH * NOUT + 255) / 256), dim3(256), 0, stream,
                           data, b_lin, out);
    }
}

// Round 10
// 151.002 us; speedup vs baseline: 1.2568x; 1.0461x over previous
//
#include <hip/hip_runtime.h>
#include <hip/hip_bf16.h>

#define SEQ   101
#define BATCH 16384
#define INP   9
#define HID   32
#define NOUT  3
#define HSlin 3232          // HID*SEQ
#define SB    (SEQ * BATCH) // flattened (s,b) cols

typedef __attribute__((ext_vector_type(8))) short short8;     // 8 bf16 (4 VGPRs)
typedef __attribute__((ext_vector_type(4))) float f32x4;      // MFMA C/D
typedef __attribute__((ext_vector_type(2))) float f32x2;      // v_pk_* pairs
typedef __attribute__((ext_vector_type(2))) unsigned u32x2;
typedef __attribute__((ext_vector_type(4))) unsigned u32x4;

#define LOG2E   1.4426950408889634f
#define N2LOG2E (-2.8853900817779268f)

__device__ __forceinline__ unsigned hi16_of(float f) {        // truncate to bf16
    return __float_as_uint(f) >> 16;
}
__device__ __forceinline__ unsigned lo16_of(float f) {        // residual as bf16
    unsigned u = __float_as_uint(f);
    float lo = f - __uint_as_float(u & 0xffff0000u);
    return __float_as_uint(lo) >> 16;
}
// one v_perm_b32: bf16-trunc of a -> bits[15:0], b -> bits[31:16]
__device__ __forceinline__ unsigned pack2(float a, float b) {
    return __builtin_amdgcn_perm(__float_as_uint(b), __float_as_uint(a), 0x07060302u);
}
__device__ __forceinline__ float losub(float f) {             // bf16 residual as float
    return f - __uint_as_float(__float_as_uint(f) & 0xffff0000u);
}
// DPP row_ror:8 — within each 16-lane row, lane i <-> lane i^8 (n=8: ror == xor)
__device__ __forceinline__ unsigned dpp8u(unsigned v) {
    return (unsigned)__builtin_amdgcn_mov_dpp((int)v, 0x128, 0xF, 0xF, true);
}
__device__ __forceinline__ float dpp8f(float v) {
    return __int_as_float(__builtin_amdgcn_mov_dpp(__float_as_int(v), 0x128, 0xF, 0xF, true));
}

// Swapped-operand scheme: gates^T = W * [x|h]^T  (verified R4-R9).
// Weights pre-scaled by log2e (i,f,o) / 2*log2e (g) so activations use raw exp2.
__global__ void prep_kernel(const float* __restrict__ W_ih, const float* __restrict__ W_hh,
                            const float* __restrict__ b_ih, const float* __restrict__ b_hh,
                            unsigned short* __restrict__ whh_hi, unsigned short* __restrict__ whh_lo,
                            unsigned short* __restrict__ wih, float* __restrict__ biasc) {
    int tid = threadIdx.x;            // 0..511 : t = tid>>6, l = tid&63
    int l   = tid & 63;
    int t   = tid >> 6;
    int row = l & 15;                 // gate-in-tile
    int g   = l >> 4;
    int gate = 16 * t + row;
    float sc = ((gate >> 5) == 2) ? (2.f * LOG2E) : LOG2E;    // g-gate: tanh needs e^{-2g}
    for (int j = 0; j < 8; ++j) {
        int u = 4 * g + (j & 3) + 16 * (j >> 2);     // pi(8g+j)
        float whh = W_hh[gate * HID + u] * sc;
        whh_hi[tid * 8 + j] = (unsigned short)hi16_of(whh);
        whh_lo[tid * 8 + j] = (unsigned short)lo16_of(whh);
        int k = 8 * g + j;
        const float* Wr = W_ih + gate * INP;
        unsigned v;
        if      (k < 8)   v = hi16_of(Wr[k] * sc);
        else if (k < 16)  v = lo16_of(Wr[k - 8] * sc);
        else if (k < 24)  v = hi16_of(Wr[k - 16] * sc);
        else if (k == 24) v = hi16_of(Wr[8] * sc);
        else if (k == 25) v = lo16_of(Wr[8] * sc);
        else if (k == 26) v = hi16_of(Wr[8] * sc);
        else              v = 0u;
        wih[tid * 8 + j] = (unsigned short)v;
    }
    if (tid < 4 * HID) {
        float bs = ((tid >> 5) == 2) ? (2.f * LOG2E) : LOG2E;
        biasc[tid] = (b_ih[tid] + b_hh[tid]) * bs;
    }
}

// Emit staged W_lin partials (base psb = s*BATCH + b0). xor8 merge via DPP
// (VALU, no DS round-trip); xor16/32 via shuffle (off critical path).
template<bool PLANES>
__device__ __forceinline__ void emit_prev(float p0, float p1, float p2,
                                          unsigned psb, float* __restrict__ dataout,
                                          int lane, int cr) {
    p0 += dpp8f(p0);          p1 += dpp8f(p1);          p2 += dpp8f(p2);
    p0 += __shfl_xor(p0, 16); p1 += __shfl_xor(p1, 16); p2 += __shfl_xor(p2, 16);
    p0 += __shfl_xor(p0, 32); p1 += __shfl_xor(p1, 32); p2 += __shfl_xor(p2, 32);
    if (PLANES) {
        if (lane < 8) {
            unsigned blk = psb + (unsigned)lane;
            dataout[0 * SB + blk] = p0;
            dataout[1 * SB + blk] = p1;
            dataout[2 * SB + blk] = p2;
        }
    } else {
        // fallback: <=2 output rows across the 8 cols; butterfly over 8 cols
        unsigned blk  = psb + (unsigned)cr;
        unsigned r    = blk / 101u;
        unsigned rmin = psb / 101u;
        bool low = (r == rmin);
        float a0 = low ? p0 : 0.f, a1 = low ? p1 : 0.f, a2 = low ? p2 : 0.f;
        float d0 = low ? 0.f : p0, d1 = low ? 0.f : p1, d2 = low ? 0.f : p2;
#pragma unroll
        for (int m = 1; m < 8; m <<= 1) {
            a0 += __shfl_xor(a0, m); a1 += __shfl_xor(a1, m); a2 += __shfl_xor(a2, m);
            d0 += __shfl_xor(d0, m); d1 += __shfl_xor(d1, m); d2 += __shfl_xor(d2, m);
        }
        int anyhi = __any(!low && lane < 8);
        if (lane == 0) {
            atomicAdd(&dataout[rmin * 3 + 0], a0);
            atomicAdd(&dataout[rmin * 3 + 1], a1);
            atomicAdd(&dataout[rmin * 3 + 2], a2);
            if (anyhi) {
                atomicAdd(&dataout[(rmin + 1u) * 3 + 0], d0);
                atomicAdd(&dataout[(rmin + 1u) * 3 + 1], d1);
                atomicAdd(&dataout[(rmin + 1u) * 3 + 2], d2);
            }
        }
    }
}

// One INDEPENDENT wave per 8 batch rows (cols 8-15 duplicate 0-7), no barriers.
// Activations split by lane-half (R9); NEW: h handoff is pack-first + DPP
// (no DS on the recurrence path), merged-rcp c-update (7 trans/unit), and
// float2 activation arithmetic targeting v_pk_* ops.
template<bool PLANES>
__global__ __launch_bounds__(64, 2) void lstm_kernel(
    const float* __restrict__ x,                 // [SEQ][BATCH][INP]
    const unsigned short* __restrict__ whh_hi_g, // [8][64][8] A-frags
    const unsigned short* __restrict__ whh_lo_g,
    const unsigned short* __restrict__ wih_g,
    const float* __restrict__ biasc,             // [4H] (pre-scaled)
    const float* __restrict__ W_lin,             // [NOUT][HSlin]
    float* __restrict__ dataout)                 // planes [3][SB] (or accp fallback)
{
    const int lane = threadIdx.x;
    const int c    = lane & 15;        // MFMA batch col
    const int cr   = c & 7;            // real batch col (8-15 duplicate 0-7)
    const bool hi8 = (lane & 8) != 0;  // this lane owns half1 (units 16+4g+q)
    const int g    = lane >> 4;
    const int b0   = blockIdx.x * 8;
    const int b    = b0 + cr;

    // Static A-fragments + per-lane bias quads (live across all steps)
    short8 whi[8], wlo[8], xw[8];
    f32x4 biasv[8];
#pragma unroll
    for (int t = 0; t < 8; ++t) {
        whi[t] = *reinterpret_cast<const short8*>(whh_hi_g + (t * 64 + lane) * 8);
        wlo[t] = *reinterpret_cast<const short8*>(whh_lo_g + (t * 64 + lane) * 8);
        xw[t]  = *reinterpret_cast<const short8*>(wih_g    + (t * 64 + lane) * 8);
        biasv[t] = *reinterpret_cast<const f32x4*>(biasc + 16 * t + 4 * g);
    }

    const bool g01 = (g < 2), g2 = (g == 2);

    f32x2 cs[2] = {{0.f, 0.f}, {0.f, 0.f}};      // c-state: my half's 4 units
    f32x2 ho[2] = {{0.f, 0.f}, {0.f, 0.f}};      // my half's h (for W_lin dot)
    u32x4 bhv = {0u, 0u, 0u, 0u};                // packed B-frag hi (persistent)
    u32x4 blv = {0u, 0u, 0u, 0u};                // packed B-frag lo (persistent)
    float xv[9];
    {
        const float* xp = x + (size_t)b * INP;           // s = 0
#pragma unroll
        for (int i = 0; i < 9; ++i) xv[i] = xp[i];
    }

    float pp0 = 0.f, pp1 = 0.f, pp2 = 0.f;               // staged W_lin partials
    unsigned psb = 0;

#pragma unroll 1
    for (int s = 0; s < SEQ; ++s) {
        // (0) this step's W_lin weights — only my half's 4 columns per plane
        unsigned blk  = (unsigned)s * BATCH + (unsigned)b;
        unsigned r    = blk / 101u;
        unsigned slot = blk - r * 101u;
        const float* wl = W_lin + slot * HID + 4 * g + (hi8 ? 16 : 0);
        float4 w0 = *(const float4*)(wl);
        float4 w1 = *(const float4*)(wl + HSlin);
        float4 w2 = *(const float4*)(wl + 2 * HSlin);

        // (1) packed-x B fragment (v_perm packing, per-g select)
        short8 xa;
        {
            unsigned hp0 = pack2(xv[0], xv[1]), hp1 = pack2(xv[2], xv[3]);
            unsigned hp2 = pack2(xv[4], xv[5]), hp3 = pack2(xv[6], xv[7]);
            unsigned lp0 = pack2(losub(xv[0]), losub(xv[1])), lp1 = pack2(losub(xv[2]), losub(xv[3]));
            unsigned lp2 = pack2(losub(xv[4]), losub(xv[5])), lp3 = pack2(losub(xv[6]), losub(xv[7]));
            unsigned h8h8 = pack2(xv[8], xv[8]);
            unsigned l8w  = __float_as_uint(losub(xv[8])) >> 16;
            u32x4 xt;
            xt[0] = g01 ? hp0 : (g2 ? lp0 : h8h8);
            xt[1] = g01 ? hp1 : (g2 ? lp1 : l8w);
            xt[2] = g01 ? hp2 : (g2 ? lp2 : 0u);
            xt[3] = g01 ? hp3 : (g2 ? lp3 : 0u);
            xa = __builtin_bit_cast(short8, xt);
        }
        // (2) h B-fragments: already packed+exchanged (persistent state)
        short8 bh = __builtin_bit_cast(short8, bhv);
        short8 bl = __builtin_bit_cast(short8, blv);

        // (3) gates^T: 8 tiles x 4 MFMA
        f32x4 acc[8];
#pragma unroll
        for (int t = 0; t < 8; ++t) {
            acc[t] = __builtin_amdgcn_mfma_f32_16x16x32_bf16(whi[t], bh, biasv[t], 0, 0, 0);
            acc[t] = __builtin_amdgcn_mfma_f32_16x16x32_bf16(wlo[t], bh, acc[t],   0, 0, 0);
            acc[t] = __builtin_amdgcn_mfma_f32_16x16x32_bf16(whi[t], bl, acc[t],   0, 0, 0);
            acc[t] = __builtin_amdgcn_mfma_f32_16x16x32_bf16(xw[t],  xa, acc[t],   0, 0, 0);
        }
        // (4) previous step's reduce + stores — hides under MFMA latency
        if (s > 0) emit_prev<PLANES>(pp0, pp1, pp2, psb, dataout, lane, cr);

        // (5) prefetch next step's x
        float xn[9];
        if (s < SEQ - 1) {
            const float* xpn = x + ((size_t)(s + 1) * BATCH + b) * INP;
#pragma unroll
            for (int i = 0; i < 9; ++i) xn[i] = xpn[i];
        }

        // (6) activations for MY half (4 units as 2 float2 pairs, v_pk math).
        //     c' = [c*(1+ei)(1+eg) + (1-eg)(1+ef)] / [(1+ef)(1+ei)(1+eg)]
        //     h  = (1-ec) / ((1+eo)(1+ec)),  ec = exp2(c' * -2log2e)
        f32x4 aI = hi8 ? acc[1] : acc[0];
        f32x4 aF = hi8 ? acc[3] : acc[2];
        f32x4 aG = hi8 ? acc[5] : acc[4];
        f32x4 aO = hi8 ? acc[7] : acc[6];
#pragma unroll
        for (int p = 0; p < 2; ++p) {
            f32x2 ef = {__builtin_amdgcn_exp2f(-aF[2*p]), __builtin_amdgcn_exp2f(-aF[2*p+1])};
            f32x2 ei = {__builtin_amdgcn_exp2f(-aI[2*p]), __builtin_amdgcn_exp2f(-aI[2*p+1])};
            f32x2 eg = {__builtin_amdgcn_exp2f(-aG[2*p]), __builtin_amdgcn_exp2f(-aG[2*p+1])};
            f32x2 pf = ef + 1.f;
            f32x2 A  = (ei + 1.f) * (eg + 1.f);
            f32x2 num = cs[p] * A + (1.f - eg) * pf;
            f32x2 den = pf * A;
            f32x2 rd = {__builtin_amdgcn_rcpf(den.x), __builtin_amdgcn_rcpf(den.y)};
            f32x2 cn = num * rd;
            cs[p] = cn;
            f32x2 eo = {__builtin_amdgcn_exp2f(-aO[2*p]), __builtin_amdgcn_exp2f(-aO[2*p+1])};
            f32x2 ec = {__builtin_amdgcn_exp2f(cn.x * N2LOG2E), __builtin_amdgcn_exp2f(cn.y * N2LOG2E)};
            f32x2 dd = (eo + 1.f) * (ec + 1.f);
            f32x2 rh = {__builtin_amdgcn_rcpf(dd.x), __builtin_amdgcn_rcpf(dd.y)};
            ho[p] = (1.f - ec) * rh;
        }
        // (6b) pack own half, DPP-exchange with twin (no DS), order into B-frags
        {
            unsigned oh01 = pack2(ho[0].x, ho[0].y);
            unsigned oh23 = pack2(ho[1].x, ho[1].y);
            unsigned ol01 = pack2(losub(ho[0].x), losub(ho[0].y));
            unsigned ol23 = pack2(losub(ho[1].x), losub(ho[1].y));
            unsigned th01 = dpp8u(oh01), th23 = dpp8u(oh23);
            unsigned tl01 = dpp8u(ol01), tl23 = dpp8u(ol23);
            bhv[0] = hi8 ? th01 : oh01;  bhv[1] = hi8 ? th23 : oh23;
            bhv[2] = hi8 ? oh01 : th01;  bhv[3] = hi8 ? oh23 : th23;
            blv[0] = hi8 ? tl01 : ol01;  blv[1] = hi8 ? tl23 : ol23;
            blv[2] = hi8 ? ol01 : tl01;  blv[3] = hi8 ? ol23 : tl23;
        }
        if (s < SEQ - 1) {
#pragma unroll
            for (int i = 0; i < 9; ++i) xv[i] = xn[i];
        }

        // (7) this step's W_lin partial — my half's 4 units only
        pp0 = w0.x * ho[0].x + w0.y * ho[0].y + w0.z * ho[1].x + w0.w * ho[1].y;
        pp1 = w1.x * ho[0].x + w1.y * ho[0].y + w1.z * ho[1].x + w1.w * ho[1].y;
        pp2 = w2.x * ho[0].x + w2.y * ho[0].y + w2.z * ho[1].x + w2.w * ho[1].y;
        psb = (unsigned)s * BATCH + (unsigned)b0;
    }
    // epilogue: emit for s = SEQ-1
    emit_prev<PLANES>(pp0, pp1, pp2, psb, dataout, lane, cr);
}

// Plane path: one wave per output row sums its 101 contiguous cols.
__global__ void finalize_planes(const float* __restrict__ planes, const float* __restrict__ b_lin,
                                float* __restrict__ out) {
    int wid = (blockIdx.x * blockDim.x + threadIdx.x) >> 6;   // row 0..16383
    int l   = threadIdx.x & 63;
    float v[3];
#pragma unroll
    for (int o = 0; o < 3; ++o) {
        const float* p = planes + (size_t)o * SB + (size_t)wid * 101;
        float t = p[l] + ((l < 37) ? p[l + 64] : 0.f);
#pragma unroll
        for (int m = 1; m < 64; m <<= 1) t += __shfl_xor(t, m);
        v[o] = t;
    }
    if (l == 0) {
        out[wid * 3 + 0] = v[0] + b_lin[0];
        out[wid * 3 + 1] = v[1] + b_lin[1];
        out[wid * 3 + 2] = v[2] + b_lin[2];
    }
}

__global__ void finalize_acc(const float* __restrict__ acc, const float* __restrict__ b_lin,
                             float* __restrict__ out) {
    int i = blockIdx.x * blockDim.x + threadIdx.x;
    if (i < BATCH * NOUT) {
        int r = i / 3;
        int o = i - r * 3;
        out[i] = acc[i] + b_lin[o];
    }
}

extern "C" void kernel_launch(void* const* d_in, const int* in_sizes, int n_in,
                              void* d_out, int out_size, void* d_ws, size_t ws_size,
                              hipStream_t stream) {
    const float* x     = (const float*)d_in[0];
    const float* W_ih  = (const float*)d_in[1];
    const float* W_hh  = (const float*)d_in[2];
    const float* b_ih  = (const float*)d_in[3];
    const float* b_hh  = (const float*)d_in[4];
    const float* W_lin = (const float*)d_in[5];
    const float* b_lin = (const float*)d_in[6];
    float* out = (float*)d_out;

    // ws: whh_hi[4096]u16 | whh_lo[4096]u16 | wih[4096]u16 | biasc[128]f32 | data...
    unsigned short* whh_hi = (unsigned short*)d_ws;
    unsigned short* whh_lo = whh_hi + 4096;
    unsigned short* wih    = whh_lo + 4096;
    float* biasc = (float*)(wih + 4096);
    float* data  = (float*)((char*)d_ws + 25600);

    size_t need_planes = 25600 + (size_t)3 * SB * sizeof(float);
    bool planes = ws_size >= need_planes;

    hipLaunchKernelGGL(prep_kernel, dim3(1), dim3(512), 0, stream,
                       W_ih, W_hh, b_ih, b_hh, whh_hi, whh_lo, wih, biasc);
    if (planes) {
        hipLaunchKernelGGL((lstm_kernel<true>), dim3(BATCH / 8), dim3(64), 0, stream,
                           x, whh_hi, whh_lo, wih, biasc, W_lin, data);
        hipLaunchKernelGGL(finalize_planes, dim3(BATCH / 4), dim3(256), 0, stream,
                           data, b_lin, out);
    } else {
        hipMemsetAsync(data, 0, 49160 * sizeof(float), stream);
        hipLaunchKernelGGL((lstm_kernel<false>), dim3(BATCH / 8), dim3(64), 0, stream,
                           x, whh_hi, whh_lo, wih, biasc, W_lin, data);
        hipLaunchKernelGGL(finalize_acc, dim3((BATCH * NOUT + 255) / 256), dim3(256), 0, stream,
                           data, b_lin, out);
    }
}

// Round 11
// 114.222 us; speedup vs baseline: 1.6616x; 1.3220x over previous
//
#include <hip/hip_runtime.h>
#include <hip/hip_bf16.h>

#define SEQ   101
#define BATCH 16384
#define INP   9
#define HID   32
#define NOUT  3
#define HSlin 3232          // HID*SEQ
#define SB    (SEQ * BATCH) // flattened (s,b) cols

typedef __attribute__((ext_vector_type(8))) _Float16 half8;   // 8 fp16 (4 VGPRs)
typedef __attribute__((ext_vector_type(8))) short short8;
typedef __attribute__((ext_vector_type(4))) float f32x4;      // MFMA C/D
typedef __attribute__((ext_vector_type(2))) float f32x2;      // v_pk_* pairs
typedef __attribute__((ext_vector_type(4))) unsigned u32x4;

#define LOG2E   1.4426950408889634f
#define N2LOG2E (-2.8853900817779268f)

// pack two f32 -> half2 in one v_cvt_pkrtz_f16_f32
__device__ __forceinline__ unsigned pkh(float a, float b) {
    return __builtin_bit_cast(unsigned, __builtin_amdgcn_cvt_pkrtz(a, b));
}
// DPP row_ror:8 — within each 16-lane row, lane i <-> lane i^8
__device__ __forceinline__ unsigned dpp8u(unsigned v) {
    return (unsigned)__builtin_amdgcn_mov_dpp((int)v, 0x128, 0xF, 0xF, true);
}
__device__ __forceinline__ float dpp8f(float v) {
    return __int_as_float(__builtin_amdgcn_mov_dpp(__float_as_int(v), 0x128, 0xF, 0xF, true));
}

// Swapped-operand scheme: gates^T = W * [x|h]^T (verified R4-R10), now fp16:
// A = fp16 weights (RTN), B = fp16 x/h (RTZ pack), fp32 accumulate.
// Weights pre-scaled by log2e (i,f,o) / 2*log2e (g) so activations use raw exp2.
// k-permutation for h: pi(8g+j) = 4g + (j&3) + 16*(j>>2)  (B-frag = own h).
// x map: k=0..8 -> W_ih column k; k>=9 -> 0.
__global__ void prep_kernel(const float* __restrict__ W_ih, const float* __restrict__ W_hh,
                            const float* __restrict__ b_ih, const float* __restrict__ b_hh,
                            unsigned short* __restrict__ whh16, unsigned short* __restrict__ wih16,
                            float* __restrict__ biasc) {
    int tid = threadIdx.x;            // 0..511 : t = tid>>6, l = tid&63
    int l   = tid & 63;
    int t   = tid >> 6;
    int row = l & 15;                 // gate-in-tile
    int g   = l >> 4;
    int gate = 16 * t + row;
    float sc = ((gate >> 5) == 2) ? (2.f * LOG2E) : LOG2E;    // g-gate: tanh needs e^{-2g}
    for (int j = 0; j < 8; ++j) {
        int u = 4 * g + (j & 3) + 16 * (j >> 2);     // pi(8g+j)
        _Float16 wh = (_Float16)(W_hh[gate * HID + u] * sc);
        whh16[tid * 8 + j] = __builtin_bit_cast(unsigned short, wh);
        int k = 8 * g + j;
        _Float16 wi = (_Float16)((k < INP) ? (W_ih[gate * INP + k] * sc) : 0.f);
        wih16[tid * 8 + j] = __builtin_bit_cast(unsigned short, wi);
    }
    if (tid < 4 * HID) {
        float bs = ((tid >> 5) == 2) ? (2.f * LOG2E) : LOG2E;
        biasc[tid] = (b_ih[tid] + b_hh[tid]) * bs;
    }
}

// Emit staged W_lin partials (base psb = s*BATCH + b0). xor8 merge via DPP;
// xor16/32 via shuffle (off critical path).
template<bool PLANES>
__device__ __forceinline__ void emit_prev(float p0, float p1, float p2,
                                          unsigned psb, float* __restrict__ dataout,
                                          int lane, int cr) {
    p0 += dpp8f(p0);          p1 += dpp8f(p1);          p2 += dpp8f(p2);
    p0 += __shfl_xor(p0, 16); p1 += __shfl_xor(p1, 16); p2 += __shfl_xor(p2, 16);
    p0 += __shfl_xor(p0, 32); p1 += __shfl_xor(p1, 32); p2 += __shfl_xor(p2, 32);
    if (PLANES) {
        if (lane < 8) {
            unsigned blk = psb + (unsigned)lane;
            dataout[0 * SB + blk] = p0;
            dataout[1 * SB + blk] = p1;
            dataout[2 * SB + blk] = p2;
        }
    } else {
        // fallback: <=2 output rows across the 8 cols; butterfly over 8 cols
        unsigned blk  = psb + (unsigned)cr;
        unsigned r    = blk / 101u;
        unsigned rmin = psb / 101u;
        bool low = (r == rmin);
        float a0 = low ? p0 : 0.f, a1 = low ? p1 : 0.f, a2 = low ? p2 : 0.f;
        float d0 = low ? 0.f : p0, d1 = low ? 0.f : p1, d2 = low ? 0.f : p2;
#pragma unroll
        for (int m = 1; m < 8; m <<= 1) {
            a0 += __shfl_xor(a0, m); a1 += __shfl_xor(a1, m); a2 += __shfl_xor(a2, m);
            d0 += __shfl_xor(d0, m); d1 += __shfl_xor(d1, m); d2 += __shfl_xor(d2, m);
        }
        int anyhi = __any(!low && lane < 8);
        if (lane == 0) {
            atomicAdd(&dataout[rmin * 3 + 0], a0);
            atomicAdd(&dataout[rmin * 3 + 1], a1);
            atomicAdd(&dataout[rmin * 3 + 2], a2);
            if (anyhi) {
                atomicAdd(&dataout[(rmin + 1u) * 3 + 0], d0);
                atomicAdd(&dataout[(rmin + 1u) * 3 + 1], d1);
                atomicAdd(&dataout[(rmin + 1u) * 3 + 2], d2);
            }
        }
    }
}

// One INDEPENDENT wave per 8 batch rows (cols 8-15 duplicate 0-7), no barriers.
// fp16 single-pass gates: 2 MFMA per tile (x-proj + h-recurrence), 16/step.
template<bool PLANES>
__global__ __launch_bounds__(64, 2) void lstm_kernel(
    const float* __restrict__ x,                 // [SEQ][BATCH][INP]
    const unsigned short* __restrict__ whh_g,    // [8][64][8] fp16 A-frags
    const unsigned short* __restrict__ wih_g,    // [8][64][8] fp16 A-frags
    const float* __restrict__ biasc,             // [4H] (pre-scaled)
    const float* __restrict__ W_lin,             // [NOUT][HSlin]
    float* __restrict__ dataout)                 // planes [3][SB] (or accp fallback)
{
    const int lane = threadIdx.x;
    const int c    = lane & 15;        // MFMA batch col
    const int cr   = c & 7;            // real batch col (8-15 duplicate 0-7)
    const bool hi8 = (lane & 8) != 0;  // this lane owns half1 (units 16+4g+q)
    const int g    = lane >> 4;
    const int b0   = blockIdx.x * 8;
    const int b    = b0 + cr;

    // Static A-fragments + per-lane bias quads (live across all steps)
    half8 whh[8], xw[8];
    f32x4 biasv[8];
#pragma unroll
    for (int t = 0; t < 8; ++t) {
        whh[t] = __builtin_bit_cast(half8, *reinterpret_cast<const short8*>(whh_g + (t * 64 + lane) * 8));
        xw[t]  = __builtin_bit_cast(half8, *reinterpret_cast<const short8*>(wih_g + (t * 64 + lane) * 8));
        biasv[t] = *reinterpret_cast<const f32x4*>(biasc + 16 * t + 4 * g);
    }

    const bool g0 = (g == 0), g1 = (g == 1);

    f32x2 cs[2] = {{0.f, 0.f}, {0.f, 0.f}};      // c-state: my half's 4 units
    f32x2 ho[2] = {{0.f, 0.f}, {0.f, 0.f}};      // my half's h (for W_lin dot)
    u32x4 bhv = {0u, 0u, 0u, 0u};                // packed fp16 h B-frag (persistent)
    float xv[9];
    {
        const float* xp = x + (size_t)b * INP;           // s = 0
#pragma unroll
        for (int i = 0; i < 9; ++i) xv[i] = xp[i];
    }

    float pp0 = 0.f, pp1 = 0.f, pp2 = 0.f;               // staged W_lin partials
    unsigned psb = 0;

#pragma unroll 1
    for (int s = 0; s < SEQ; ++s) {
        // (0) this step's W_lin weights — only my half's 4 columns per plane
        unsigned blk  = (unsigned)s * BATCH + (unsigned)b;
        unsigned r    = blk / 101u;
        unsigned slot = blk - r * 101u;
        const float* wl = W_lin + slot * HID + 4 * g + (hi8 ? 16 : 0);
        float4 w0 = *(const float4*)(wl);
        float4 w1 = *(const float4*)(wl + HSlin);
        float4 w2 = *(const float4*)(wl + 2 * HSlin);

        // (1) fp16 x B-fragment: g=0 supplies x0..x7 (k=0..7), g=1 supplies x8 (k=8)
        short8 xa;
        {
            unsigned x01 = pkh(xv[0], xv[1]), x23 = pkh(xv[2], xv[3]);
            unsigned x45 = pkh(xv[4], xv[5]), x67 = pkh(xv[6], xv[7]);
            unsigned x8z = pkh(xv[8], 0.f);
            u32x4 xt;
            xt[0] = g0 ? x01 : (g1 ? x8z : 0u);
            xt[1] = g0 ? x23 : 0u;
            xt[2] = g0 ? x45 : 0u;
            xt[3] = g0 ? x67 : 0u;
            xa = __builtin_bit_cast(short8, xt);
        }
        // (2) h B-fragment: already packed+exchanged (persistent state)
        half8 bh = __builtin_bit_cast(half8, bhv);

        // (3) gates^T: 8 tiles x 2 MFMA (fp16, fp32-accum)
        f32x4 acc[8];
#pragma unroll
        for (int t = 0; t < 8; ++t) {
            acc[t] = __builtin_amdgcn_mfma_f32_16x16x32_f16(xw[t], __builtin_bit_cast(half8, xa), biasv[t], 0, 0, 0);
            acc[t] = __builtin_amdgcn_mfma_f32_16x16x32_f16(whh[t], bh, acc[t], 0, 0, 0);
        }
        // (4) previous step's reduce + stores — hides under MFMA latency
        if (s > 0) emit_prev<PLANES>(pp0, pp1, pp2, psb, dataout, lane, cr);

        // (5) prefetch next step's x
        float xn[9];
        if (s < SEQ - 1) {
            const float* xpn = x + ((size_t)(s + 1) * BATCH + b) * INP;
#pragma unroll
            for (int i = 0; i < 9; ++i) xn[i] = xpn[i];
        }

        // (6) activations for MY half (4 units as 2 float2 pairs, v_pk math).
        //     c' = [c*(1+ei)(1+eg) + (1-eg)(1+ef)] / [(1+ef)(1+ei)(1+eg)]
        //     h  = (1-ec) / ((1+eo)(1+ec)),  ec = exp2(c' * -2log2e)
        f32x4 aI = hi8 ? acc[1] : acc[0];
        f32x4 aF = hi8 ? acc[3] : acc[2];
        f32x4 aG = hi8 ? acc[5] : acc[4];
        f32x4 aO = hi8 ? acc[7] : acc[6];
#pragma unroll
        for (int p = 0; p < 2; ++p) {
            f32x2 ef = {__builtin_amdgcn_exp2f(-aF[2*p]), __builtin_amdgcn_exp2f(-aF[2*p+1])};
            f32x2 ei = {__builtin_amdgcn_exp2f(-aI[2*p]), __builtin_amdgcn_exp2f(-aI[2*p+1])};
            f32x2 eg = {__builtin_amdgcn_exp2f(-aG[2*p]), __builtin_amdgcn_exp2f(-aG[2*p+1])};
            f32x2 pf = ef + 1.f;
            f32x2 A  = (ei + 1.f) * (eg + 1.f);
            f32x2 num = cs[p] * A + (1.f - eg) * pf;
            f32x2 den = pf * A;
            f32x2 rd = {__builtin_amdgcn_rcpf(den.x), __builtin_amdgcn_rcpf(den.y)};
            f32x2 cn = num * rd;
            cs[p] = cn;
            f32x2 eo = {__builtin_amdgcn_exp2f(-aO[2*p]), __builtin_amdgcn_exp2f(-aO[2*p+1])};
            f32x2 ec = {__builtin_amdgcn_exp2f(cn.x * N2LOG2E), __builtin_amdgcn_exp2f(cn.y * N2LOG2E)};
            f32x2 dd = (eo + 1.f) * (ec + 1.f);
            f32x2 rh = {__builtin_amdgcn_rcpf(dd.x), __builtin_amdgcn_rcpf(dd.y)};
            ho[p] = (1.f - ec) * rh;
        }
        // (6b) pack own half to fp16, DPP-exchange with twin, order into B-frag
        {
            unsigned oh01 = pkh(ho[0].x, ho[0].y);
            unsigned oh23 = pkh(ho[1].x, ho[1].y);
            unsigned th01 = dpp8u(oh01), th23 = dpp8u(oh23);
            bhv[0] = hi8 ? th01 : oh01;  bhv[1] = hi8 ? th23 : oh23;
            bhv[2] = hi8 ? oh01 : th01;  bhv[3] = hi8 ? oh23 : th23;
        }
        if (s < SEQ - 1) {
#pragma unroll
            for (int i = 0; i < 9; ++i) xv[i] = xn[i];
        }

        // (7) this step's W_lin partial — my half's 4 units only
        pp0 = w0.x * ho[0].x + w0.y * ho[0].y + w0.z * ho[1].x + w0.w * ho[1].y;
        pp1 = w1.x * ho[0].x + w1.y * ho[0].y + w1.z * ho[1].x + w1.w * ho[1].y;
        pp2 = w2.x * ho[0].x + w2.y * ho[0].y + w2.z * ho[1].x + w2.w * ho[1].y;
        psb = (unsigned)s * BATCH + (unsigned)b0;
    }
    // epilogue: emit for s = SEQ-1
    emit_prev<PLANES>(pp0, pp1, pp2, psb, dataout, lane, cr);
}

// Plane path: one wave per output row sums its 101 contiguous cols.
__global__ void finalize_planes(const float* __restrict__ planes, const float* __restrict__ b_lin,
                                float* __restrict__ out) {
    int wid = (blockIdx.x * blockDim.x + threadIdx.x) >> 6;   // row 0..16383
    int l   = threadIdx.x & 63;
    float v[3];
#pragma unroll
    for (int o = 0; o < 3; ++o) {
        const float* p = planes + (size_t)o * SB + (size_t)wid * 101;
        float t = p[l] + ((l < 37) ? p[l + 64] : 0.f);
#pragma unroll
        for (int m = 1; m < 64; m <<= 1) t += __shfl_xor(t, m);
        v[o] = t;
    }
    if (l == 0) {
        out[wid * 3 + 0] = v[0] + b_lin[0];
        out[wid * 3 + 1] = v[1] + b_lin[1];
        out[wid * 3 + 2] = v[2] + b_lin[2];
    }
}

__global__ void finalize_acc(const float* __restrict__ acc, const float* __restrict__ b_lin,
                             float* __restrict__ out) {
    int i = blockIdx.x * blockDim.x + threadIdx.x;
    if (i < BATCH * NOUT) {
        int r = i / 3;
        int o = i - r * 3;
        out[i] = acc[i] + b_lin[o];
    }
}

extern "C" void kernel_launch(void* const* d_in, const int* in_sizes, int n_in,
                              void* d_out, int out_size, void* d_ws, size_t ws_size,
                              hipStream_t stream) {
    const float* x     = (const float*)d_in[0];
    const float* W_ih  = (const float*)d_in[1];
    const float* W_hh  = (const float*)d_in[2];
    const float* b_ih  = (const float*)d_in[3];
    const float* b_hh  = (const float*)d_in[4];
    const float* W_lin = (const float*)d_in[5];
    const float* b_lin = (const float*)d_in[6];
    float* out = (float*)d_out;

    // ws: whh16[4096]u16 | wih16[4096]u16 | biasc[128]f32 | (pad) | data...
    unsigned short* whh16 = (unsigned short*)d_ws;
    unsigned short* wih16 = whh16 + 4096;
    float* biasc = (float*)(wih16 + 4096);
    float* data  = (float*)((char*)d_ws + 25600);

    size_t need_planes = 25600 + (size_t)3 * SB * sizeof(float);
    bool planes = ws_size >= need_planes;

    hipLaunchKernelGGL(prep_kernel, dim3(1), dim3(512), 0, stream,
                       W_ih, W_hh, b_ih, b_hh, whh16, wih16, biasc);
    if (planes) {
        hipLaunchKernelGGL((lstm_kernel<true>), dim3(BATCH / 8), dim3(64), 0, stream,
                           x, whh16, wih16, biasc, W_lin, data);
        hipLaunchKernelGGL(finalize_planes, dim3(BATCH / 4), dim3(256), 0, stream,
                           data, b_lin, out);
    } else {
        hipMemsetAsync(data, 0, 49160 * sizeof(float), stream);
        hipLaunchKernelGGL((lstm_kernel<false>), dim3(BATCH / 8), dim3(64), 0, stream,
                           x, whh16, wih16, biasc, W_lin, data);
        hipLaunchKernelGGL(finalize_acc, dim3((BATCH * NOUT + 255) / 256), dim3(256), 0, stream,
                           data, b_lin, out);
    }
}